// Round 1
// baseline (307.756 us; speedup 1.0000x reference)
//
#include <hip/hip_runtime.h>

typedef unsigned short u16;
typedef __bf16 bf16x8 __attribute__((ext_vector_type(8)));
typedef float f32x4 __attribute__((ext_vector_type(4)));
typedef unsigned short u16x4 __attribute__((ext_vector_type(4)));
typedef unsigned short u16x8 __attribute__((ext_vector_type(8)));

#define BB 2
#define SS 2048
#define EE 1024
#define HH 16
#define DD 64

static __device__ inline u16 f2bf(float f) {
    union { float f; unsigned int u; } v; v.f = f;
    unsigned int u = v.u;
    unsigned int r = (u + 0x7FFFu + ((u >> 16) & 1u)) >> 16;  // RNE
    return (u16)r;
}

// ---------------- K0a: transpose Wq/Wk/Wv [H,E,D] f32 -> WT [3*1024][1024] bf16 ----------------
__global__ __launch_bounds__(256) void transpose_w_kernel(
    const float* __restrict__ Wq, const float* __restrict__ Wk, const float* __restrict__ Wv,
    u16* __restrict__ WT)
{
    const int z = blockIdx.z;
    const int h = blockIdx.y;
    const int e0 = blockIdx.x * 64;
    const float* W = (z == 0) ? Wq : (z == 1) ? Wk : Wv;
    __shared__ float t_lds[64][68];
    const int tid = threadIdx.x;
#pragma unroll
    for (int it = 0; it < 4; ++it) {
        int s = tid + it * 256;            // 1024 float4 slots
        int i = s >> 4, d4 = (s & 15) * 4; // i = e-offset, d4 = d
        const float4 v = *reinterpret_cast<const float4*>(&W[((size_t)h * EE + e0 + i) * DD + d4]);
        t_lds[i][d4 + 0] = v.x; t_lds[i][d4 + 1] = v.y;
        t_lds[i][d4 + 2] = v.z; t_lds[i][d4 + 3] = v.w;
    }
    __syncthreads();
#pragma unroll
    for (int it = 0; it < 4; ++it) {
        int s = tid + it * 256;
        int d = s >> 4, i4 = (s & 15) * 4;
        u16x4 o;
        o[0] = f2bf(t_lds[i4 + 0][d]); o[1] = f2bf(t_lds[i4 + 1][d]);
        o[2] = f2bf(t_lds[i4 + 2][d]); o[3] = f2bf(t_lds[i4 + 3][d]);
        *reinterpret_cast<u16x4*>(&WT[((size_t)z * 1024 + h * 64 + d) * EE + e0 + i4]) = o;
    }
}

// ---------------- K0b: W2T[e][h*D+d] = sum_o Wo[h,d,o]*Wf[h*O+o,e]; b2 += bo-part (+bf at h==0) ----------------
__global__ __launch_bounds__(256) void build_w2t_kernel(
    const float* __restrict__ Wo, const float* __restrict__ bo,
    const float* __restrict__ Wf, const float* __restrict__ bfin,
    u16* __restrict__ W2T, float* __restrict__ b2)
{
    const int h = blockIdx.y;
    const int e0 = blockIdx.x * 64;
    __shared__ float wo_lds[64][65];  // [d][o]
    __shared__ float wf_lds[64][65];  // [o][i]
    const int tid = threadIdx.x;
#pragma unroll
    for (int it = 0; it < 4; ++it) {
        int s = tid + it * 256;
        int r = s >> 4, c4 = (s & 15) * 4;
        const float4 a = *reinterpret_cast<const float4*>(&Wo[((size_t)h * 64 + r) * 64 + c4]);
        wo_lds[r][c4 + 0] = a.x; wo_lds[r][c4 + 1] = a.y; wo_lds[r][c4 + 2] = a.z; wo_lds[r][c4 + 3] = a.w;
        const float4 b = *reinterpret_cast<const float4*>(&Wf[((size_t)(h * 64 + r)) * EE + e0 + c4]);
        wf_lds[r][c4 + 0] = b.x; wf_lds[r][c4 + 1] = b.y; wf_lds[r][c4 + 2] = b.z; wf_lds[r][c4 + 3] = b.w;
    }
    __syncthreads();
    const int d = tid & 63;
    const int i0 = (tid >> 6) * 16;
#pragma unroll
    for (int ii = 0; ii < 16; ++ii) {
        int i = i0 + ii;
        float acc = 0.f;
#pragma unroll 8
        for (int o = 0; o < 64; ++o) acc += wo_lds[d][o] * wf_lds[o][i];
        W2T[((size_t)(e0 + i)) * 1024 + h * 64 + d] = f2bf(acc);
    }
    if (tid < 64) {
        int i = tid;
        float acc = 0.f;
        for (int o = 0; o < 64; ++o) acc += bo[h * 64 + o] * wf_lds[o][i];
        if (h == 0) acc += bfin[e0 + i];
        atomicAdd(&b2[e0 + i], acc);
    }
}

// ---------------- K1: QKV projection GEMM: [4096,1024]x[1024,1024] per z, out bf16 [B,H,S,D] ----------------
__global__ __launch_bounds__(256) void gemm_qkv_kernel(
    const float* __restrict__ query, const float* __restrict__ key, const float* __restrict__ value,
    const u16* __restrict__ WT,
    const float* __restrict__ bq, const float* __restrict__ bk, const float* __restrict__ bv,
    u16* __restrict__ qbf, u16* __restrict__ kbf, u16* __restrict__ vbf)
{
    const int z = blockIdx.z;
    const float* A   = (z == 0) ? query : (z == 1) ? key : value;
    const float* bia = (z == 0) ? bq    : (z == 1) ? bk  : bv;
    u16* outp        = (z == 0) ? qbf   : (z == 1) ? kbf : vbf;
    const u16* BT = WT + (size_t)z * 1024 * 1024;

    const int m0 = blockIdx.y * 128;
    const int n0 = blockIdx.x * 128;

    __shared__ u16 a_lds[128][72];
    __shared__ u16 b_lds[128][72];

    const int tid = threadIdx.x;
    const int lane = tid & 63;
    const int w = tid >> 6;
    const int wm = w >> 1, wn = w & 1;
    const int lrow = lane & 15;
    const int lgrp = lane >> 4;

    f32x4 acc[4][4] = {};

    for (int k0 = 0; k0 < 1024; k0 += 64) {
#pragma unroll
        for (int it = 0; it < 8; ++it) {
            int s = tid + it * 256;            // 2048 float4 slots (128x64 f32)
            int row = s >> 4, c4 = (s & 15) * 4;
            const float4 v = *reinterpret_cast<const float4*>(&A[(size_t)(m0 + row) * 1024 + k0 + c4]);
            u16x4 o;
            o[0] = f2bf(v.x); o[1] = f2bf(v.y); o[2] = f2bf(v.z); o[3] = f2bf(v.w);
            *reinterpret_cast<u16x4*>(&a_lds[row][c4]) = o;
        }
#pragma unroll
        for (int it = 0; it < 4; ++it) {
            int s = tid + it * 256;            // 1024 slots of 8 bf16 (128x64)
            int row = s >> 3, c8 = (s & 7) * 8;
            *reinterpret_cast<u16x8*>(&b_lds[row][c8]) =
                *reinterpret_cast<const u16x8*>(&BT[(size_t)(n0 + row) * 1024 + k0 + c8]);
        }
        __syncthreads();

#pragma unroll
        for (int kk = 0; kk < 2; ++kk) {
            bf16x8 af[4], bfr[4];
#pragma unroll
            for (int i = 0; i < 4; ++i)
                af[i] = *reinterpret_cast<const bf16x8*>(&a_lds[wm * 64 + i * 16 + lrow][kk * 32 + lgrp * 8]);
#pragma unroll
            for (int j = 0; j < 4; ++j)
                bfr[j] = *reinterpret_cast<const bf16x8*>(&b_lds[wn * 64 + j * 16 + lrow][kk * 32 + lgrp * 8]);
#pragma unroll
            for (int i = 0; i < 4; ++i)
#pragma unroll
                for (int j = 0; j < 4; ++j)
                    acc[i][j] = __builtin_amdgcn_mfma_f32_16x16x32_bf16(af[i], bfr[j], acc[i][j], 0, 0, 0);
        }
        __syncthreads();
    }

#pragma unroll
    for (int i = 0; i < 4; ++i) {
#pragma unroll
        for (int j = 0; j < 4; ++j) {
            int n = n0 + wn * 64 + j * 16 + lrow;
            int h = n >> 6, d = n & 63;
            float bb = bia[n];
#pragma unroll
            for (int r = 0; r < 4; ++r) {
                int m = m0 + wm * 64 + i * 16 + lgrp * 4 + r;
                int b = m >> 11, srow = m & 2047;
                outp[((size_t)(b * HH + h) * SS + srow) * DD + d] = f2bf(acc[i][j][r] + bb);
            }
        }
    }
}

// ---------------- K2: flash attention, QBLK=64 (4 waves x 16 rows), KV tile 64 ----------------
__global__ __launch_bounds__(256) void attn_kernel(
    const u16* __restrict__ qbf, const u16* __restrict__ kbf, const u16* __restrict__ vbf,
    const float* __restrict__ qmask, const float* __restrict__ kmask,
    u16* __restrict__ att)
{
    const int qt = blockIdx.x;
    const int h  = blockIdx.y;
    const int b  = blockIdx.z;
    const int tid = threadIdx.x;
    const int w = tid >> 6;
    const int lane = tid & 63;
    const int lrow = lane & 15, lgrp = lane >> 4;

    __shared__ u16 k_lds[64][72];
    __shared__ u16 vt_lds[64][72];
    __shared__ u16 p_lds[4][16][72];

    const size_t bh = (size_t)(b * HH + h);
    const u16* Kb = kbf + bh * SS * DD;
    const u16* Vb = vbf + bh * SS * DD;
    const int q0 = qt * 64 + w * 16;

    bf16x8 aq[2];
#pragma unroll
    for (int kk = 0; kk < 2; ++kk)
        aq[kk] = *reinterpret_cast<const bf16x8*>(&qbf[(bh * SS + q0 + lrow) * DD + kk * 32 + lgrp * 8]);

    float m_run[4], l_run[4];
    f32x4 acc_o[4] = {};
#pragma unroll
    for (int r = 0; r < 4; ++r) { m_run[r] = -1e30f; l_run[r] = 0.f; }

    const float sscale = 0.125f * 1.44269504f;  // 1/sqrt(D) in log2 domain

    for (int t0 = 0; t0 < SS; t0 += 64) {
#pragma unroll
        for (int it = 0; it < 2; ++it) {
            int s = tid + it * 256;            // 512 slots of 8 bf16 (64x64)
            int row = s >> 3, c8 = (s & 7) * 8;
            *reinterpret_cast<u16x8*>(&k_lds[row][c8]) =
                *reinterpret_cast<const u16x8*>(&Kb[(size_t)(t0 + row) * DD + c8]);
        }
#pragma unroll
        for (int it = 0; it < 2; ++it) {
            int s = tid + it * 256;
            int row = s >> 3, c8 = (s & 7) * 8; // row = t-local, c8 = d base
            u16x8 vv = *reinterpret_cast<const u16x8*>(&Vb[(size_t)(t0 + row) * DD + c8]);
#pragma unroll
            for (int j = 0; j < 8; ++j) vt_lds[c8 + j][row] = vv[j];
        }
        __syncthreads();

        // QK^T: 4 n-subtiles of 16 keys
        f32x4 sc[4];
#pragma unroll
        for (int nt = 0; nt < 4; ++nt) {
            f32x4 a = {};
#pragma unroll
            for (int kk = 0; kk < 2; ++kk) {
                bf16x8 bk8 = *reinterpret_cast<const bf16x8*>(&k_lds[nt * 16 + lrow][kk * 32 + lgrp * 8]);
                a = __builtin_amdgcn_mfma_f32_16x16x32_bf16(aq[kk], bk8, a, 0, 0, 0);
            }
            sc[nt] = a;
        }

        float kmv[4];
#pragma unroll
        for (int nt = 0; nt < 4; ++nt) kmv[nt] = kmask[(size_t)b * SS + t0 + nt * 16 + lrow];
#pragma unroll
        for (int nt = 0; nt < 4; ++nt)
#pragma unroll
            for (int r = 0; r < 4; ++r)
                sc[nt][r] = (kmv[nt] != 0.f) ? sc[nt][r] * sscale : -1e30f;

#pragma unroll
        for (int r = 0; r < 4; ++r) {
            float v = fmaxf(fmaxf(sc[0][r], sc[1][r]), fmaxf(sc[2][r], sc[3][r]));
            v = fmaxf(v, __shfl_xor(v, 1));
            v = fmaxf(v, __shfl_xor(v, 2));
            v = fmaxf(v, __shfl_xor(v, 4));
            v = fmaxf(v, __shfl_xor(v, 8));
            float mnew = fmaxf(m_run[r], v);
            float alpha = exp2f(m_run[r] - mnew);
            m_run[r] = mnew;
            l_run[r] *= alpha;
#pragma unroll
            for (int nf = 0; nf < 4; ++nf) acc_o[nf][r] *= alpha;
            float psum = 0.f;
#pragma unroll
            for (int nt = 0; nt < 4; ++nt) {
                float p = (kmv[nt] != 0.f) ? exp2f(sc[nt][r] - mnew) : 0.f;
                psum += p;
                p_lds[w][lgrp * 4 + r][nt * 16 + lrow] = f2bf(p);
            }
            psum += __shfl_xor(psum, 1);
            psum += __shfl_xor(psum, 2);
            psum += __shfl_xor(psum, 4);
            psum += __shfl_xor(psum, 8);
            l_run[r] += psum;
        }
        __syncthreads();

        // PV
#pragma unroll
        for (int kk = 0; kk < 2; ++kk) {
            bf16x8 ap = *reinterpret_cast<const bf16x8*>(&p_lds[w][lrow][kk * 32 + lgrp * 8]);
#pragma unroll
            for (int nf = 0; nf < 4; ++nf) {
                bf16x8 bv8 = *reinterpret_cast<const bf16x8*>(&vt_lds[nf * 16 + lrow][kk * 32 + lgrp * 8]);
                acc_o[nf] = __builtin_amdgcn_mfma_f32_16x16x32_bf16(ap, bv8, acc_o[nf], 0, 0, 0);
            }
        }
        __syncthreads();
    }

#pragma unroll
    for (int r = 0; r < 4; ++r) {
        int srow = q0 + lgrp * 4 + r;
        float qm = qmask[(size_t)b * SS + srow];
        float inv = (l_run[r] > 0.f && qm != 0.f) ? 1.f / l_run[r] : 0.f;
#pragma unroll
        for (int nf = 0; nf < 4; ++nf)
            att[((size_t)b * SS + srow) * 1024 + h * 64 + nf * 16 + lrow] = f2bf(acc_o[nf][r] * inv);
    }
}

// ---------------- K3: final GEMM: att[4096,1024] bf16 x W2T -> out f32 + b2 ----------------
__global__ __launch_bounds__(256) void gemm_final_kernel(
    const u16* __restrict__ A, const u16* __restrict__ BT,
    const float* __restrict__ b2, float* __restrict__ out)
{
    const int m0 = blockIdx.y * 128;
    const int n0 = blockIdx.x * 128;

    __shared__ u16 a_lds[128][72];
    __shared__ u16 b_lds[128][72];

    const int tid = threadIdx.x;
    const int lane = tid & 63;
    const int w = tid >> 6;
    const int wm = w >> 1, wn = w & 1;
    const int lrow = lane & 15;
    const int lgrp = lane >> 4;

    f32x4 acc[4][4] = {};

    for (int k0 = 0; k0 < 1024; k0 += 64) {
#pragma unroll
        for (int it = 0; it < 4; ++it) {
            int s = tid + it * 256;
            int row = s >> 3, c8 = (s & 7) * 8;
            *reinterpret_cast<u16x8*>(&a_lds[row][c8]) =
                *reinterpret_cast<const u16x8*>(&A[(size_t)(m0 + row) * 1024 + k0 + c8]);
        }
#pragma unroll
        for (int it = 0; it < 4; ++it) {
            int s = tid + it * 256;
            int row = s >> 3, c8 = (s & 7) * 8;
            *reinterpret_cast<u16x8*>(&b_lds[row][c8]) =
                *reinterpret_cast<const u16x8*>(&BT[(size_t)(n0 + row) * 1024 + k0 + c8]);
        }
        __syncthreads();

#pragma unroll
        for (int kk = 0; kk < 2; ++kk) {
            bf16x8 af[4], bfr[4];
#pragma unroll
            for (int i = 0; i < 4; ++i)
                af[i] = *reinterpret_cast<const bf16x8*>(&a_lds[wm * 64 + i * 16 + lrow][kk * 32 + lgrp * 8]);
#pragma unroll
            for (int j = 0; j < 4; ++j)
                bfr[j] = *reinterpret_cast<const bf16x8*>(&b_lds[wn * 64 + j * 16 + lrow][kk * 32 + lgrp * 8]);
#pragma unroll
            for (int i = 0; i < 4; ++i)
#pragma unroll
                for (int j = 0; j < 4; ++j)
                    acc[i][j] = __builtin_amdgcn_mfma_f32_16x16x32_bf16(af[i], bfr[j], acc[i][j], 0, 0, 0);
        }
        __syncthreads();
    }

#pragma unroll
    for (int i = 0; i < 4; ++i) {
#pragma unroll
        for (int j = 0; j < 4; ++j) {
            int n = n0 + wn * 64 + j * 16 + lrow;
            float bb = b2[n];
#pragma unroll
            for (int r = 0; r < 4; ++r) {
                int m = m0 + wm * 64 + i * 16 + lgrp * 4 + r;
                out[(size_t)m * 1024 + n] = acc[i][j][r] + bb;
            }
        }
    }
}

extern "C" void kernel_launch(void* const* d_in, const int* in_sizes, int n_in,
                              void* d_out, int out_size, void* d_ws, size_t ws_size,
                              hipStream_t stream) {
    const float* query = (const float*)d_in[0];
    const float* key   = (const float*)d_in[1];
    const float* value = (const float*)d_in[2];
    const float* qmask = (const float*)d_in[3];
    const float* kmask = (const float*)d_in[4];
    const float* Wq = (const float*)d_in[5];
    const float* bq = (const float*)d_in[6];
    const float* Wk = (const float*)d_in[7];
    const float* bk = (const float*)d_in[8];
    const float* Wv = (const float*)d_in[9];
    const float* bv = (const float*)d_in[10];
    const float* Wo = (const float*)d_in[11];
    const float* bo = (const float*)d_in[12];
    const float* Wf = (const float*)d_in[13];
    const float* bfin = (const float*)d_in[14];
    float* out = (float*)d_out;

    char* ws = (char*)d_ws;
    u16*   WT  = (u16*)  (ws + 0);          // 3*1024*1024*2 = 6291456
    u16*   W2T = (u16*)  (ws + 6291456);    // 1024*1024*2   = 2097152
    float* b2  = (float*)(ws + 8388608);    // 4096
    u16*   qbf = (u16*)  (ws + 8392704);    // 8388608
    u16*   kbf = (u16*)  (ws + 16781312);   // 8388608
    u16*   vbf = (u16*)  (ws + 25169920);   // 8388608
    u16*   att = (u16*)  (ws + 33558528);   // 8388608  (end ~41.9 MB)

    hipMemsetAsync(b2, 0, 1024 * sizeof(float), stream);
    transpose_w_kernel<<<dim3(16, 16, 3), 256, 0, stream>>>(Wq, Wk, Wv, WT);
    build_w2t_kernel<<<dim3(16, 16), 256, 0, stream>>>(Wo, bo, Wf, bfin, W2T, b2);
    gemm_qkv_kernel<<<dim3(8, 32, 3), 256, 0, stream>>>(query, key, value, WT, bq, bk, bv, qbf, kbf, vbf);
    attn_kernel<<<dim3(32, 16, 2), 256, 0, stream>>>(qbf, kbf, vbf, qmask, kmask, att);
    gemm_final_kernel<<<dim3(8, 32), 256, 0, stream>>>(att, W2T, b2, out);
}